// Round 2
// baseline (37.829 us; speedup 1.0000x reference)
//
#include <hip/hip_runtime.h>
#include <math.h>

// ---- constants from the reference ----
#define ALPHA_F   0.02f
#define BETA_F    0.015f
#define E_EX_F    0.1f
#define ZEEMAN_F  (5.79e-05f * 2.0f * 0.1f)
#define PI_F      3.14159265358979323846f
#define TWO_PI_F  6.28318530717958647692f
#define SCALE_F   ((float)(1e-11 / 6.582e-16))   // T_EVO/HBAR ~= 15193.56
#define DEPH_F    1e-4f                          // 1e7 * 1e-11

__device__ __forceinline__ float wrap_pi(float d) {
    float w = fmodf(d + PI_F, TWO_PI_F);
    if (w < 0.f) w += TWO_PI_F;
    return w - PI_F;
}

// ---- main kernel: physics + per-block reductions over a contiguous chunk ----
__global__ __launch_bounds__(256) void main_k(
    const float* __restrict__ inp,   // (B,16)
    const float* __restrict__ sre,   // (B,2)
    const float* __restrict__ sim,   // (B,2)
    const float* __restrict__ exf,   // (D,3)
    const float* __restrict__ gap,   // (1,)
    float* __restrict__ out,         // whole output buffer, guarded
    long long out_size,
    double* __restrict__ blkBerry,
    double* __restrict__ blkDang,
    float* __restrict__ firstA,
    float* __restrict__ lastA,
    int chunk,                       // elements per block, multiple of 256
    long long B, int Dex)
{
    const int t = threadIdx.x;

    // uniform constants, computed redundantly per thread (L2-cached, scalarizable)
    float j0 = 0.f, j1 = 0.f, j2 = 0.f;
    for (int d = 0; d < Dex; ++d) {
        j0 += exf[d * 3 + 0];
        j1 += exf[d * 3 + 1];
        j2 += exf[d * 3 + 2];
    }
    const float invD = 1.f / (float)Dex;
    const float cx = E_EX_F * (j0 * invD);
    const float cy = E_EX_F * (j1 * invD);
    const float hz = E_EX_F * (j2 * invD) + ZEEMAN_F + gap[0];
    const float Ef = expf(-SCALE_F * DEPH_F);   // exp(damp)

    const long long psi_off = 3 * B;
    const long long mom_off = 7 * B;

    const long long base = (long long)blockIdx.x * chunk;
    const int ntile = chunk >> 8;

    __shared__ float sAng[256];
    __shared__ float sPrevLast;

    double v1 = 0.0, v2 = 0.0;
    float ang = 0.f;

    for (int tile = 0; tile < ntile; ++tile) {
        const long long i = base + (long long)tile * 256 + t;

        const float2 k  = *reinterpret_cast<const float2*>(inp + i * 16);
        const float2 re = *reinterpret_cast<const float2*>(sre + i * 2);
        const float2 im = *reinterpret_cast<const float2*>(sim + i * 2);

        // normalize spinor
        const float nrm = re.x * re.x + re.y * re.y + im.x * im.x + im.y * im.y;
        const float inv = rsqrtf(nrm);
        const float a0r = re.x * inv, a0i = im.x * inv;
        const float a1r = re.y * inv, a1i = im.y * inv;

        // effective field
        const float hx = ALPHA_F * k.y + BETA_F * k.x + cx;
        const float hy = -ALPHA_F * k.x - BETA_F * k.y + cy;

        // closed-form U = exp(-i*SCALE*H + damp*I)
        const float r  = sqrtf(hx * hx + hy * hy + hz * hz);
        const float th = SCALE_F * r;
        float s, c;
        __sincosf(th, &s, &c);
        const float rs = fmaxf(r, 1e-37f);
        const float f  = Ef * s / rs;
        const float Ec = Ef * c;

        // U = [Ec - i f hz,  -f hy - i f hx;  f hy - i f hx,  Ec + i f hz]
        const float p0r = Ec * a0r + f * hz * a0i + (-f * hy) * a1r + f * hx * a1i;
        const float p0i = Ec * a0i - f * hz * a0r + (-f * hy) * a1i - f * hx * a1r;
        const float p1r = Ec * a1r - f * hz * a1i + ( f * hy) * a0r + f * hx * a0i;
        const float p1i = Ec * a1i + f * hz * a1r + ( f * hy) * a0i - f * hx * a0r;

        // observables
        const float crr = p0r * p1r + p0i * p1i;   // Re(p0*conj(p1))
        const float cri = p0i * p1r - p0r * p1i;   // Im(p0*conj(p1))
        const float sx = 2.f * crr;
        const float sy = 2.f * cri;
        const float sz = (p0r * p0r + p0i * p0i) - (p1r * p1r + p1i * p1i);

        // guarded stores
        const long long o3 = i * 3;
        if (o3 + 2 < out_size) {
            out[o3 + 0] = sx;
            out[o3 + 1] = sy;
            out[o3 + 2] = sz;
        }
        const long long o4 = psi_off + i * 4;
        if (o4 + 3 < out_size) {
            *reinterpret_cast<float4*>(out + o4) = make_float4(p0r, p0i, p1r, p1i);
        }
        const long long o2 = mom_off + i * 2;
        if (o2 + 1 < out_size) {
            *reinterpret_cast<float2*>(out + o2) = k;
        }

        const float dph = atan2f(p1i, p1r) - atan2f(p0i, p0r);
        ang = atan2f(sy, sx);

        sAng[t] = ang;
        __syncthreads();

        float dang = (t < 255) ? wrap_pi(sAng[t + 1] - ang) : 0.f;
        if (tile > 0 && t == 0) v2 += (double)wrap_pi(ang - sPrevLast);
        if (tile == 0 && t == 0) firstA[blockIdx.x] = ang;

        v1 += (double)dph;
        v2 += (double)dang;

        __syncthreads();
        if (t == 255) sPrevLast = ang;
    }
    if (t == 255) lastA[blockIdx.x] = ang;

    // deterministic block reduction of two doubles
    for (int o = 32; o; o >>= 1) {
        v1 += __shfl_down(v1, o);
        v2 += __shfl_down(v2, o);
    }
    __shared__ double r1[4], r2[4];
    const int wid = t >> 6, lane = t & 63;
    if (lane == 0) { r1[wid] = v1; r2[wid] = v2; }
    __syncthreads();
    if (t == 0) {
        blkBerry[blockIdx.x] = r1[0] + r1[1] + r1[2] + r1[3];
        blkDang[blockIdx.x]  = r2[0] + r2[1] + r2[2] + r2[3];
    }
}

// ---- final scalar reduction ----
__global__ __launch_bounds__(256) void final_k(
    const double* __restrict__ blkBerry, const double* __restrict__ blkDang,
    const float* __restrict__ firstA, const float* __restrict__ lastA,
    int nblk, long long B, float* __restrict__ out, long long out_size)
{
    const int t = threadIdx.x;
    double s1 = 0.0, s2 = 0.0;
    for (int b = t; b < nblk; b += 256) {
        s1 += blkBerry[b];
        s2 += blkDang[b];
    }
    for (int b = t; b < nblk - 1; b += 256) {
        s2 += (double)wrap_pi(firstA[b + 1] - lastA[b]);
    }
    for (int o = 32; o; o >>= 1) {
        s1 += __shfl_down(s1, o);
        s2 += __shfl_down(s2, o);
    }
    __shared__ double r1[4], r2[4];
    const int wid = t >> 6, lane = t & 63;
    if (lane == 0) { r1[wid] = s1; r2[wid] = s2; }
    __syncthreads();
    if (t == 0 && out_size >= 2) {
        const double sum_dph  = r1[0] + r1[1] + r1[2] + r1[3];
        const double sum_dang = r2[0] + r2[1] + r2[2] + r2[3];
        double bp = sum_dph / (double)B;
        double w = fmod(bp + (double)M_PI, 2.0 * (double)M_PI);
        if (w < 0.0) w += 2.0 * (double)M_PI;
        out[out_size - 2] = (float)(w - (double)M_PI);                        // berry_phase
        out[out_size - 1] = (float)nearbyint(sum_dang / (2.0 * (double)M_PI)); // charge
    }
}

extern "C" void kernel_launch(void* const* d_in, const int* in_sizes, int n_in,
                              void* d_out, int out_size, void* d_ws, size_t ws_size,
                              hipStream_t stream) {
    (void)n_in;
    const float* inp = (const float*)d_in[0];
    const float* sre = (const float*)d_in[1];
    const float* sim = (const float*)d_in[2];
    const float* exf = (const float*)d_in[3];
    const float* gap = (const float*)d_in[4];

    const long long B   = (long long)in_sizes[0] / 16;   // 1048576
    const int       Dex = in_sizes[3] / 3;               // 16

    // pick the largest block count whose ws partials fit in ws_size
    // per block: 8 (berry) + 8 (dang) + 4 (firstA) + 4 (lastA) = 24 bytes
    int nblk = 64;
    const int cands[7] = {4096, 2048, 1024, 512, 256, 128, 64};
    for (int ci = 0; ci < 7; ++ci) {
        const int c = cands[ci];
        if (B % ((long long)c * 256) == 0 && (size_t)c * 24 + 64 <= ws_size) {
            nblk = c;
            break;
        }
    }
    const int chunk = (int)(B / nblk);   // multiple of 256

    char* ws = (char*)d_ws;
    double* blkBerry = (double*)(ws);
    double* blkDang  = (double*)(ws + (size_t)nblk * 8);
    float*  firstA   = (float*) (ws + (size_t)nblk * 16);
    float*  lastA    = (float*) (ws + (size_t)nblk * 20);

    float* out = (float*)d_out;

    main_k<<<nblk, 256, 0, stream>>>(inp, sre, sim, exf, gap,
                                     out, (long long)out_size,
                                     blkBerry, blkDang, firstA, lastA,
                                     chunk, B, Dex);
    final_k<<<1, 256, 0, stream>>>(blkBerry, blkDang, firstA, lastA,
                                   nblk, B, out, (long long)out_size);
}